// Round 13
// baseline (128.192 us; speedup 1.0000x reference)
//
#include <hip/hip_runtime.h>
#include <stdint.h>

#define NB 8
#define NPRED 25200
#define NTOP 1000
#define NCLS 80
#define CONF_T 0.25f
#define IOU_THR 0.45f
#define MAXWH 4096.0f
#define CAP 2048
#define NBINS 1025
#define SBLK 128
#define SBPB 197   // ceil(25200/128): 197*128 = 25216

typedef unsigned long long u64;

__device__ __forceinline__ u64 shfl_u64(u64 v, int src) {
    int lo = __shfl((int)(unsigned)v, src);
    int hi = __shfl((int)(unsigned)(v >> 32), src);
    return ((u64)(unsigned)hi << 32) | (unsigned)lo;
}

// ---------------------------------------------------------------------------
// K1: score/class per pred. 1024 threads / 128 preds = 8 threads/pred,
// 10 classes each, combined by a 3-stage __shfl_xor tree (d = 1,2,4; take
// partner only if STRICTLY greater). Serial compare chain 40 -> 13;
// 2 blocks/CU x 16 waves to hide the staging drain. Tie-break: by induction
// the lower-class-range thread wins ties at every stage, so thread h==0
// holds the first-occurrence-of-max -- semantics identical to the 2-thread
// version (absmax 0.0 lineage). Staging via global_load_lds width=16.
// (Round-12 bench died on an INFRA error "container failed twice" with no
// counters -- resubmitting unchanged, as in r9->r10 where the identical
// resubmit ran clean. Kernel audited: loops bounded, LDS 43.5 KB, no OOB.)
// ---------------------------------------------------------------------------
__global__ __launch_bounds__(1024) void k_score(const float* __restrict__ x,
                                                float* __restrict__ msc,
                                                int* __restrict__ cls) {
#pragma clang fp contract(off)
    __shared__ __align__(16) float sm[SBLK * 85];
    const int b = blockIdx.x / SBPB;
    const int blk = blockIdx.x % SBPB;
    const int t = threadIdx.x;
    const int wave = t >> 6, lane = t & 63;
    const long long TOT4 = (long long)NB * NPRED * 85 / 4;  // 4,284,000
    const long long base4 = ((long long)b * NPRED + (long long)blk * SBLK) * 85 / 4;
    const float4* x4 = (const float4*)x;
    const int tile4 = SBLK * 85 / 4;  // 2720

    for (int k = 0; k < 3; ++k) {
        int ib = k * 1024 + wave * 64;     // wave-uniform lds base (float4 units)
        int fi = ib + lane;
        if (fi < tile4) {
            long long gi = base4 + fi;
            if (gi >= TOT4) gi = TOT4 - 1;  // tail clamp (outputs guarded below)
            __builtin_amdgcn_global_load_lds(
                (const __attribute__((address_space(1))) void*)(x4 + gi),
                (__attribute__((address_space(3))) void*)(sm + (size_t)ib * 4),
                16, 0, 0);
        }
    }
    __syncthreads();

    const int p = t >> 3;        // pred within block [0,128)
    const int h = t & 7;         // class-slice: [h*10, h*10+10)
    const int pred = blk * SBLK + p;
    const float* rowp = &sm[p * 85];
    float obj = rowp[4];                       // same-address broadcast
    const int cb = 5 + h * 10;
    float best = rowp[cb];
    int bid = h * 10;
    for (int c = 1; c < 10; ++c) {
        float v = rowp[cb + c];
        if (v > best) { best = v; bid = h * 10 + c; }  // strict >: first occurrence
    }
#pragma unroll
    for (int d = 1; d <= 4; d <<= 1) {         // combine tree: 1,2,4
        float obest = __shfl_xor(best, d);
        int obid = __shfl_xor(bid, d);
        if (obest > best) { best = obest; bid = obid; }  // strictly greater only
    }
    if (h == 0 && pred < NPRED) {
        float score = obj * best;
        int q = b * NPRED + pred;
        msc[q] = (score > CONF_T) ? score : -1.0f;
        cls[q] = bid;
    }
}

// ---------------------------------------------------------------------------
// K2 (fused tail) = round-11 verbatim (best total, 127.9 us).
// Pipeline: vectorized float4 msc stash -> pass A 1025-bin LDS hist ->
// wave-0 suffix-scan (exact per-bin rank bases hbase[] + boundary bin B) ->
// scatter slot=atomicAdd(hbase) -> fused rank+gather (r = base + #{same-bin
// keys < mine}; x-row loads issued before the count loop to hide latency)
// -> bm[80][16] rank bitmask -> one-wave-per-class ballot greedy -> masked
// write. Exactness: keys unique -> rank is an exact permutation, ties
// idx-ascending = stable top_k; cross-class IoU exactly 0 (stripes 4094
// apart -> clipped wh=0); same-class IoU identical expression; absmax 0.0
// for 11 rounds. CAP-drop + >64-per-class fallback semantics unchanged.
// ---------------------------------------------------------------------------
__global__ __launch_bounds__(1024) void k_fused(const float* __restrict__ x,
                                                const float* __restrict__ msc,
                                                const int* __restrict__ cls,
                                                float* __restrict__ out) {
#pragma clang fp contract(off)
    __shared__ __align__(16) unsigned char uni[CAP * 8];  // keys | bm+sup
    __shared__ unsigned hh[NBINS];       // pass-A counts (persist for rank)
    __shared__ unsigned hbase[NBINS];    // suffix bases -> scatter cursors
    __shared__ __align__(16) float4 obx[NTOP];   // un-offset xyxy
    __shared__ float oco[NTOP];                  // cls * 4096
    __shared__ float osc[NTOP];                  // score
    __shared__ int   ocl[NTOP];                  // class id, -1 if invalid
    __shared__ int sB;
    __shared__ int ovf;
    u64* keys = (u64*)uni;
    const int b = blockIdx.x, t = threadIdx.x;
    const float4* ms4 = (const float4*)(msc + (size_t)b * NPRED);  // 16B-aligned

    // single global pass, vectorized: 7 float4 regs/thread (7*4*1024 >= 25200)
    float4 sv4[7];
#pragma unroll
    for (int k = 0; k < 7; ++k) {
        int f4i = t + k * 1024;
        sv4[k] = (f4i < NPRED / 4) ? ms4[f4i]
                                   : make_float4(-1.f, -1.f, -1.f, -1.f);
    }

    for (int i = t; i < NBINS; i += 1024) hh[i] = 0;
    keys[t] = ~0ULL; keys[t + 1024] = ~0ULL;
    if (t < NTOP) ocl[t] = -1;
    if (t == 0) { ovf = 0; sB = 0; }
    __syncthreads();

    // pass A: per-batch histogram of score bits (LDS atomics, from regs)
#pragma unroll
    for (int k = 0; k < 7; ++k) {
        const float* f = (const float*)&sv4[k];
#pragma unroll
        for (int j = 0; j < 4; ++j) {
            float s = f[j];
            if (s > CONF_T) {
                unsigned bits = __float_as_uint(s);
                int bin = (int)(bits >> 14) - 0xFA00;
                bin = bin < 0 ? 0 : (bin > 1024 ? 1024 : bin);
                atomicAdd(&hh[bin], 1u);
            }
        }
    }
    __syncthreads();

    if (t < 64) {  // wave 0: suffix bases for ALL bins + boundary bin B
        const int lane = t;
        const int hi2 = 1024 - 16 * lane;       // lane chunk: bins [hi2-15, hi2]
        unsigned lc[16];
        unsigned sum = 0;
#pragma unroll
        for (int k = 0; k < 16; ++k) { lc[k] = hh[hi2 - k]; sum += lc[k]; }
        if (lane == 63) sum += hh[0];
        unsigned v = sum;
        for (int d = 1; d < 64; d <<= 1) {
            unsigned o = __shfl_up(v, d);
            if (lane >= d) v += o;
        }
        unsigned excl = v - sum;                // count strictly above my chunk
        // per-bin rank bases: hbase[bin] = #candidates in bins > bin
        unsigned run = excl;
#pragma unroll
        for (int k = 0; k < 16; ++k) { hbase[hi2 - k] = run; run += lc[k]; }
        if (lane == 63) hbase[0] = run;         // bin 0 (run excludes hh[0])
        // boundary bin B
        u64 ball = __ballot(v >= NTOP);
        int B = 0;
        if (ball != 0) {
            int sel = __builtin_ctzll(ball);
            if (lane == sel) {
                unsigned r2 = excl;
                for (int k = 0; k < 16; ++k) {
                    r2 += lc[k];
                    if (r2 >= NTOP) { B = hi2 - k; break; }
                }
            }
            B = __shfl(B, sel);
        }
        if (lane == 0) sB = B;
    }
    __syncthreads();
    const int B = sB;

    // pass B: scatter candidates (bin >= B) to their bin segment (from regs)
#pragma unroll
    for (int k = 0; k < 7; ++k) {
        const float* f = (const float*)&sv4[k];
#pragma unroll
        for (int j = 0; j < 4; ++j) {
            float s = f[j];
            if (s > CONF_T) {
                unsigned bits = __float_as_uint(s);
                int bin = (int)(bits >> 14) - 0xFA00;
                bin = bin < 0 ? 0 : (bin > 1024 ? 1024 : bin);
                if (bin >= B) {
                    unsigned slot = atomicAdd(&hbase[bin], 1u);
                    if (slot < (unsigned)CAP)
                        keys[slot] = ((u64)(~bits) << 32)
                                   | (unsigned)((t + k * 1024) * 4 + j);
                }
            }
        }
    }
    __syncthreads();

    // fused rank + gather: exact rank = base + #{same-bin keys < mine};
    // the x-row loads are issued BEFORE the count loop (address is rank-
    // independent) so their latency hides under the LDS counting.
    {
        auto binOf = [](u64 kk) -> int {
            unsigned bits = ~(unsigned)(kk >> 32);
            int bin = (int)(bits >> 14) - 0xFA00;
            return bin < 0 ? 0 : (bin > 1024 ? 1024 : bin);
        };
#pragma unroll
        for (int pp = 0; pp < 2; ++pp) {
            int i = t + pp * 1024;
            u64 my = keys[i];
            if (my == ~0ULL) continue;
            // issue gather loads first (independent of rank)
            unsigned p = (unsigned)my;
            const float* xp = x + ((size_t)b * NPRED + p) * 85;
            float xc = xp[0], yc = xp[1], w = xp[2], h = xp[3];
            int cid = cls[(size_t)b * NPRED + p];
            // rank count (LDS, ~25-wide segment, no dependent chain)
            int bin = binOf(my);
            int e2 = (int)hbase[bin];           // base + n (post-scatter cursor)
            if (e2 > CAP) e2 = CAP;
            int base = e2 - (int)hh[bin];
            if (base < 0) base = 0;
            unsigned r = (unsigned)base;
            for (int j = base; j < e2; ++j) r += (keys[j] < my) ? 1u : 0u;
            if (r < (unsigned)NTOP) {
                float hw = w * 0.5f, hh2 = h * 0.5f;
                obx[r] = make_float4(xc - hw, yc - hh2, xc + hw, yc + hh2);
                oco[r] = (float)cid * MAXWH;
                osc[r] = __uint_as_float(~(unsigned)(my >> 32));
                ocl[r] = cid;
            }
        }
    }
    __syncthreads();    // keys dead; overlay per-class rank bitmasks + sup

    u64* bm = (u64*)uni;                  // [80][16] u64 = 10240 B
    unsigned char* sup = uni + 10240;     // 1000 B
    for (int i = t; i < NCLS * 16; i += 1024) bm[i] = 0;
    if (t < NTOP) sup[t] = 0;
    __syncthreads();
    if (t < NTOP && ocl[t] >= 0)
        atomicOr(&bm[ocl[t] * 16 + (t >> 6)], 1ull << (t & 63));
    __syncthreads();

    // ---- per-class ballot greedy: one wave per class, lane = rank order ----
    {
        const int wave = t >> 6, lane = t & 63;
        for (int c2 = wave; c2 < NCLS; c2 += 16) {
            u64 w = (lane < 16) ? bm[c2 * 16 + lane] : 0ull;
            int cum = 0, myw = -1, rem = 0;
            u64 myword = 0;
#pragma unroll
            for (int ww = 0; ww < 16; ++ww) {
                u64 wv = shfl_u64(w, ww);
                int pc = __popcll(wv);
                if (myw < 0 && lane < cum + pc) { myw = ww; rem = lane - cum; myword = wv; }
                cum += pc;
            }
            int n2 = cum;
            if (n2 == 0) continue;
            if (n2 > 64) { ovf = 1; continue; }   // benign race (all write 1)
            bool active = (lane < n2);
            int rank = 0;
            float ax1v = 0.f, ay1v = 0.f, ax2v = 0.f, ay2v = 0.f, arv = 0.f;
            if (active) {
                int pos = 0, r = rem;   // select rem-th set bit of myword
#pragma unroll
                for (int wd = 32; wd >= 1; wd >>= 1) {
                    u64 mask = ((1ull << wd) - 1ull) << pos;
                    int cc = __popcll(myword & mask);
                    if (r >= cc) { r -= cc; pos += wd; }
                }
                rank = myw * 64 + pos;
                float4 A = obx[rank]; float cA = oco[rank];
                ax1v = A.x + cA; ay1v = A.y + cA;
                ax2v = A.z + cA; ay2v = A.w + cA;
                arv = (ax2v - ax1v) * (ay2v - ay1v);
            }
            u64 alive = (n2 >= 64) ? ~0ull : ((1ull << n2) - 1ull);
            u64 kept = 0;
            while (alive) {
                int i = (int)__builtin_ctzll(alive);
                u64 bit = 1ull << i;
                kept |= bit;
                float bx1 = __shfl(ax1v, i), by1 = __shfl(ay1v, i);
                float bx2 = __shfl(ax2v, i), by2 = __shfl(ay2v, i);
                float bar = __shfl(arv, i);
                float ltx = fmaxf(bx1, ax1v), lty = fmaxf(by1, ay1v);
                float rbx = fminf(bx2, ax2v), rby = fminf(by2, ay2v);
                float ww2 = fmaxf(rbx - ltx, 0.0f), hh3 = fmaxf(rby - lty, 0.0f);
                float inter = ww2 * hh3;
                float iou = inter / (((bar + arv) - inter) + 1e-9f);
                u64 suppr = __ballot(iou > IOU_THR);
                alive &= ~(suppr | bit);
            }
            if (active) sup[rank] = ((kept >> lane) & 1ull) ? 0 : 1;
        }
    }
    __syncthreads();

    // exact serial fallback for classes with >64 candidates (P ~ 1e-40)
    if (ovf && t == 0) {
        for (int c2 = 0; c2 < NCLS; ++c2) {
            int n2 = 0;
            for (int w2 = 0; w2 < 16; ++w2) n2 += __popcll(bm[c2 * 16 + w2]);
            if (n2 <= 64) continue;
            for (int a2 = 0; a2 < NTOP; ++a2) {
                if (ocl[a2] != c2 || sup[a2]) continue;
                float4 A = obx[a2]; float cA = oco[a2];
                float ax1 = A.x + cA, ay1 = A.y + cA;
                float ax2 = A.z + cA, ay2 = A.w + cA;
                float areaA = (ax2 - ax1) * (ay2 - ay1);
                for (int d2 = a2 + 1; d2 < NTOP; ++d2) {
                    if (ocl[d2] != c2 || sup[d2]) continue;
                    float4 Bb = obx[d2];
                    float bx1 = Bb.x + cA, by1 = Bb.y + cA;
                    float bx2 = Bb.z + cA, by2 = Bb.w + cA;
                    float ltx = fmaxf(ax1, bx1), lty = fmaxf(ay1, by1);
                    float rbx = fminf(ax2, bx2), rby = fminf(ay2, by2);
                    float ww = fmaxf(rbx - ltx, 0.0f), hh3 = fmaxf(rby - lty, 0.0f);
                    float inter = ww * hh3;
                    float areaB = (bx2 - bx1) * (by2 - by1);
                    float iou = inter / (((areaA + areaB) - inter) + 1e-9f);
                    if (iou > IOU_THR) sup[d2] = 1;
                }
            }
        }
    }
    __syncthreads();

    // masked output write
    if (t < NTOP) {
        bool keep = (ocl[t] >= 0) && (sup[t] == 0);
        float4 o = obx[t];
        size_t d6 = ((size_t)b * NTOP + t) * 6;
        out[d6 + 0] = keep ? o.x : 0.0f;
        out[d6 + 1] = keep ? o.y : 0.0f;
        out[d6 + 2] = keep ? o.z : 0.0f;
        out[d6 + 3] = keep ? o.w : 0.0f;
        out[d6 + 4] = keep ? osc[t] : 0.0f;
        out[d6 + 5] = keep ? (float)ocl[t] : 0.0f;
    }
}

// ---------------------------------------------------------------------------
extern "C" void kernel_launch(void* const* d_in, const int* in_sizes, int n_in,
                              void* d_out, int out_size, void* d_ws, size_t ws_size,
                              hipStream_t stream) {
    const float* x = (const float*)d_in[0];
    char* ws = (char*)d_ws;
    float* msc = (float*)(ws);                       //      0 .. 806400
    int* cls = (int*)(ws + 806400);                  // 806400 .. 1612800

    k_score<<<NB * SBPB, 1024, 0, stream>>>(x, msc, cls);
    k_fused<<<NB, 1024, 0, stream>>>(x, msc, cls, (float*)d_out);
}